// Round 1
// baseline (669.640 us; speedup 1.0000x reference)
//
#include <hip/hip_runtime.h>

typedef __attribute__((ext_vector_type(4))) float f4;
typedef __attribute__((ext_vector_type(8))) short s8;

__device__ __forceinline__ unsigned short f2bf(float x){
  unsigned u = __float_as_uint(x);
  u += 0x7fffu + ((u >> 16) & 1u);
  return (unsigned short)(u >> 16);
}
__device__ __forceinline__ float lrelu(float v){ return v > 0.f ? v : 0.2f * v; }

// ---------------- prep 1: zero accumulators + p/q = W @ a_src / a_dst ----------------
__global__ void prep_pq(const float* __restrict__ Wg, const float* __restrict__ a_src,
                        const float* __restrict__ a_dst, float* __restrict__ pq,
                        float* __restrict__ zbase){
  int tid = blockIdx.x * 256 + threadIdx.x;
  for (int i = tid; i < 6156; i += gridDim.x * 256) zbase[i] = 0.f;  // Craw3,Craw1,den3,den1
  int wid = tid >> 6, lane = tid & 63;
  for (int task = wid; task < 4096; task += gridDim.x * 4){
    int g = task >> 10, isq = (task >> 9) & 1, r = task & 511;
    const float* w = Wg + ((g * 512 + r) << 9);
    const float* a = (isq ? a_dst : a_src) + g * 512;
    float s = 0.f;
    for (int i = lane; i < 512; i += 64) s += w[i] * a[i];
    for (int off = 32; off; off >>= 1) s += __shfl_down(s, off);
    if (lane == 0) pq[task] = s;
  }
}

// ---------------- prep 2: W2^T, W0^T as bf16 (n-major, contiguous k) ----------------
__global__ void prep_wt(const float* __restrict__ Wg, unsigned short* __restrict__ W2T,
                        unsigned short* __restrict__ W0T){
  __shared__ float tile[32][33];
  const int b = blockIdx.x;
  const int m = b >> 8;                      // 0: W2 -> W2T, 1: W0 -> W0T
  const int kb = (b & 15) * 32;
  const int nb = ((b >> 4) & 15) * 32;
  const float* W = Wg + (m == 0 ? 2 * 262144 : 0);
  unsigned short* WT = (m == 0) ? W2T : W0T;
  const int tx = threadIdx.x & 31, ty = threadIdx.x >> 5;
  #pragma unroll
  for (int i = 0; i < 32; i += 8) tile[ty + i][tx] = W[(kb + ty + i) * 512 + nb + tx];
  __syncthreads();
  #pragma unroll
  for (int i = 0; i < 32; i += 8) WT[(nb + ty + i) * 512 + kb + tx] = f2bf(tile[tx][ty + i]);
}

// ---------------- prep 3: exercise scalars + HE_g = exer_emb @ W_g ----------------
__global__ void prep_he(const float* __restrict__ exer, const float* __restrict__ Wg,
                        const float* __restrict__ pq, float* __restrict__ asE,
                        float* __restrict__ adE, float* __restrict__ HE2,
                        float* __restrict__ HE0){
  const int b = blockIdx.x;           // 0..11
  const int g = (b < 6) ? 0 : 2;
  const int e = b % 6;
  __shared__ float xs[512];
  const int t = threadIdx.x;          // 512
  xs[t] = exer[e * 512 + t];
  __syncthreads();
  const int wid = t >> 6, lane = t & 63;
  if (wid < 4){
    int gg = g + (wid >> 1), isq = wid & 1;
    const float* v = pq + gg * 1024 + isq * 512;
    float s = 0.f;
    for (int i = lane; i < 512; i += 64) s += xs[i] * v[i];
    for (int off = 32; off; off >>= 1) s += __shfl_down(s, off);
    if (lane == 0) (isq ? adE : asE)[gg * 6 + e] = s;
  }
  const float* W = Wg + g * 262144;
  float acc = 0.f;
  for (int k = 0; k < 512; k++) acc += xs[k] * W[k * 512 + t];
  ((g == 0) ? HE0 : HE2)[e * 512 + t] = acc;
}

// ---------------- main fused kernel: per-row GAT receive + fused GEMM + send accum ----------------
template<int DEG>
__launch_bounds__(512)
__global__ void gat_rows(const float* __restrict__ x, float* __restrict__ outp,
                         const unsigned short* __restrict__ WT,
                         const float* __restrict__ pq, int gA, int gB,
                         const float* __restrict__ asE, const float* __restrict__ adE,
                         const float* __restrict__ HE, const float* __restrict__ bA,
                         const int* __restrict__ idx,
                         float* __restrict__ Craw, float* __restrict__ den, int nrows)
{
  __shared__ __align__(16) float sPA[512], sQA[512], sPB[512], sBA[512];
  __shared__ __align__(16) float sHE[3072];
  __shared__ __align__(16) float sCraw[3072];
  __shared__ float sAlphaS[64];
  __shared__ float sAlphaE[64][4];
  __shared__ int   sEidx[64][4];
  __shared__ float sW[64][4];
  __shared__ float sASE[6], sADE[6], sDen[6];

  const int tid = threadIdx.x;
  { int i = tid; if (i < 512){ sPA[i]=pq[gA*1024+i]; sQA[i]=pq[gA*1024+512+i]; sPB[i]=pq[gB*1024+i]; sBA[i]=bA[i]; } }
  for (int i = tid; i < 3072; i += 512){ sHE[i] = HE[i]; sCraw[i] = 0.f; }
  if (tid < 6){ sASE[tid] = asE[gA*6+tid]; sADE[tid] = adE[gB*6+tid]; sDen[tid] = 0.f; }
  __syncthreads();

  const int wid = tid >> 6, lane = tid & 63;
  const int rg = wid & 3, ch = wid >> 2;        // 4 row-groups x 2 col-halves
  const int l16 = lane & 15, lhi = lane >> 4;
  const int rlA = rg * 16 + l16;
  const int rA  = blockIdx.x * 64 + rlA;
  const int rAc = min(rA, nrows - 1);
  const float* xrow = x + rAc * 512;

  f4 acc[16];
  #pragma unroll
  for (int t = 0; t < 16; t++) acc[t] = (f4){0.f, 0.f, 0.f, 0.f};

  float dP = 0.f, dQ = 0.f, dB = 0.f;
  const unsigned short* wtBase = WT + (ch * 256 + l16) * 512 + lhi * 8;

  #pragma unroll 1
  for (int s = 0; s < 16; s++){
    const int k0 = s * 32 + lhi * 8;
    f4 a0 = *(const f4*)(xrow + k0);
    f4 a1 = *(const f4*)(xrow + k0 + 4);
    if (ch == 0){
      f4 p0 = *(const f4*)&sPA[k0], p1 = *(const f4*)&sPA[k0+4];
      f4 q0 = *(const f4*)&sQA[k0], q1 = *(const f4*)&sQA[k0+4];
      f4 b0 = *(const f4*)&sPB[k0], b1 = *(const f4*)&sPB[k0+4];
      #pragma unroll
      for (int i = 0; i < 4; i++){
        dP += a0[i]*p0[i] + a1[i]*p1[i];
        dQ += a0[i]*q0[i] + a1[i]*q1[i];
        dB += a0[i]*b0[i] + a1[i]*b1[i];
      }
    }
    s8 af;
    #pragma unroll
    for (int i = 0; i < 4; i++){ af[i] = (short)f2bf(a0[i]); af[4+i] = (short)f2bf(a1[i]); }
    const unsigned short* wt = wtBase + s * 32;
    #pragma unroll
    for (int t = 0; t < 16; t++){
      s8 bf = *(const s8*)(wt + t * 16 * 512);
      acc[t] = __builtin_amdgcn_mfma_f32_16x16x32_bf16(af, bf, acc[t], 0, 0, 0);
    }
  }

  if (ch == 0){
    dP += __shfl_xor(dP, 16); dP += __shfl_xor(dP, 32);
    dQ += __shfl_xor(dQ, 16); dQ += __shfl_xor(dQ, 32);
    dB += __shfl_xor(dB, 16); dB += __shfl_xor(dB, 32);
    if (lhi == 0){
      const int rl = rlA, r = blockIdx.x * 64 + rl;
      const bool valid = (r < nrows);
      float scS = lrelu(dP + dQ);
      int ei[DEG]; float sc[DEG];
      #pragma unroll
      for (int j = 0; j < DEG; j++){ ei[j] = valid ? idx[r*DEG + j] : 0; sc[j] = lrelu(sASE[ei[j]] + dQ); }
      float m = scS;
      #pragma unroll
      for (int j = 0; j < DEG; j++) m = fmaxf(m, sc[j]);
      float eS = __expf(scS - m), sum = eS;
      float ev[DEG];
      #pragma unroll
      for (int j = 0; j < DEG; j++){ ev[j] = __expf(sc[j] - m); sum += ev[j]; }
      float inv = 1.f / sum;
      sAlphaS[rl] = valid ? eS * inv : 0.f;
      #pragma unroll
      for (int j = 0; j < DEG; j++){
        sAlphaE[rl][j] = valid ? ev[j] * inv : 0.f;
        sEidx[rl][j] = ei[j];
        float w = valid ? __expf(lrelu(dB + sADE[ei[j]])) : 0.f;
        sW[rl][j] = w;
        if (valid) atomicAdd(&sDen[ei[j]], w);
      }
    }
  }
  __syncthreads();

  // epilogue: out = x + alpha_self*(x@W) + sum_j alpha_j*HE[e_j] + b
  #pragma unroll
  for (int t = 0; t < 16; t++){
    const int c = ch * 256 + t * 16 + l16;
    #pragma unroll
    for (int j = 0; j < 4; j++){
      const int rl = rg * 16 + lhi * 4 + j;
      const int r = blockIdx.x * 64 + rl;
      if (r < nrows){
        float v = x[r * 512 + c] + sAlphaS[rl] * acc[t][j] + sBA[c];
        #pragma unroll
        for (int d = 0; d < DEG; d++) v += sAlphaE[rl][d] * sHE[sEidx[rl][d] * 512 + c];
        outp[r * 512 + c] = v;
      }
    }
  }

  // send-side: Craw[e] += w * x_row ; den[e] += w   (shift-0 softmax numerator/denominator)
  for (int rl = 0; rl < 64; rl++){
    const int r = blockIdx.x * 64 + rl;
    if (r >= nrows) break;
    float xv = x[r * 512 + tid];
    #pragma unroll
    for (int d = 0; d < DEG; d++)
      sCraw[sEidx[rl][d] * 512 + tid] += sW[rl][d] * xv;
  }
  __syncthreads();
  for (int i = tid; i < 3072; i += 512) atomicAdd(&Craw[i], sCraw[i]);
  if (tid < 6) atomicAdd(&den[tid], sDen[tid]);
}

// ---------------- finalize B (GAT1) and C (GAT3) for the 6 exercises ----------------
__global__ void finalize_bc(const float* __restrict__ exer, const float* __restrict__ Wg,
                            const float* __restrict__ asE, const float* __restrict__ adE,
                            const float* __restrict__ Craw3, const float* __restrict__ den3,
                            const float* __restrict__ Craw1, const float* __restrict__ den1,
                            const float* __restrict__ b_gat, float* __restrict__ B,
                            float* __restrict__ C){
  const int b = blockIdx.x;          // 0..11
  const int isC = (b >= 6) ? 1 : 0;
  const int e = b % 6;
  const int g = isC ? 3 : 1;
  const float* Craw = isC ? Craw3 : Craw1;
  const float* den  = isC ? den3  : den1;
  __shared__ float mix[512];
  const int t = threadIdx.x;          // 512
  float aS = asE[g*6 + e], aD = adE[g*6 + e];
  float wself = __expf(lrelu(aS + aD));
  float dn = den[e] + wself;
  mix[t] = (Craw[e*512 + t] + wself * exer[e*512 + t]) / dn;
  __syncthreads();
  const float* W = Wg + g * 262144;
  float acc = 0.f;
  for (int k = 0; k < 512; k++) acc += mix[k] * W[k*512 + t];
  acc += b_gat[g*512 + t];
  (isC ? C : B)[e*512 + t] = acc;
}

// ---------------- final exercise attention + output ----------------
__global__ void finalize_exer(const float* __restrict__ exer, const float* __restrict__ B,
                              const float* __restrict__ C, const float* __restrict__ attn_w,
                              const float* __restrict__ attn_b, float* __restrict__ outE){
  __shared__ float s1[6], s2[6];
  const int t = threadIdx.x, wid = t >> 6, lane = t & 63;
  for (int task = wid; task < 12; task += 8){
    int e = task >> 1, which = task & 1;
    const float* w = attn_w + (which + 1) * 1024;
    const float* X = exer + e * 512;
    const float* Y = (which ? C : B) + e * 512;
    float s = 0.f;
    for (int i = lane; i < 512; i += 64) s += X[i] * w[i] + Y[i] * w[512 + i];
    for (int off = 32; off; off >>= 1) s += __shfl_down(s, off);
    if (lane == 0) (which ? s2 : s1)[e] = s + attn_b[which + 1];
  }
  __syncthreads();
  for (int i = t; i < 3072; i += 512){
    int e = i >> 9;
    float a = s1[e], b = s2[e];
    float m = fmaxf(a, b);
    float ea = __expf(a - m), eb = __expf(b - m);
    float inv = 1.f / (ea + eb);
    outE[i] = exer[i] + (ea * inv) * B[i] + (eb * inv) * C[i];
  }
}

extern "C" void kernel_launch(void* const* d_in, const int* in_sizes, int n_in,
                              void* d_out, int out_size, void* d_ws, size_t ws_size,
                              hipStream_t stream){
  const float* kn     = (const float*)d_in[0];
  const float* exer   = (const float*)d_in[1];
  const float* stu    = (const float*)d_in[2];
  const float* Wg     = (const float*)d_in[3];
  const float* a_src  = (const float*)d_in[4];
  const float* a_dst  = (const float*)d_in[5];
  const float* b_gat  = (const float*)d_in[6];
  const float* attn_w = (const float*)d_in[7];
  const float* attn_b = (const float*)d_in[8];
  const int*   e_ke   = (const int*)d_in[9];    // row 0 = src (exercise ids), len 2048
  const int*   e_ue   = (const int*)d_in[11];   // row 0 = src (exercise ids), len 150000
  float* out = (float*)d_out;

  unsigned short* W2T = (unsigned short*)d_ws;
  unsigned short* W0T = W2T + 262144;
  float* pq    = (float*)(W0T + 262144);
  float* asE   = pq + 4096;
  float* adE   = asE + 24;
  float* HE2   = adE + 24;
  float* HE0   = HE2 + 3072;
  float* Craw3 = HE0 + 3072;
  float* Craw1 = Craw3 + 3072;
  float* den3  = Craw1 + 3072;
  float* den1  = den3 + 6;
  float* Bb    = den1 + 6;
  float* Cc    = Bb + 3072;

  hipLaunchKernelGGL(prep_pq, dim3(256), dim3(256), 0, stream, Wg, a_src, a_dst, pq, Craw3);
  hipLaunchKernelGGL(prep_wt, dim3(512), dim3(256), 0, stream, Wg, W2T, W0T);
  hipLaunchKernelGGL(prep_he, dim3(12), dim3(512), 0, stream, exer, Wg, pq, asE, adE, HE2, HE0);

  // students: receive GAT2 (gA=2), send GAT3 (gB=3)
  hipLaunchKernelGGL((gat_rows<3>), dim3((50000 + 63) / 64), dim3(512), 0, stream,
                     stu, out + 265216, W2T, pq, 2, 3, asE, adE, HE2, b_gat + 2*512,
                     e_ue, Craw3, den3, 50000);
  // knowledge: receive GAT0 (gA=0), send GAT1 (gB=1); kn_out = kn + D (softmax over singleton = 1)
  hipLaunchKernelGGL((gat_rows<4>), dim3(8), dim3(512), 0, stream,
                     kn, out, W0T, pq, 0, 1, asE, adE, HE0, b_gat,
                     e_ke, Craw1, den1, 512);

  hipLaunchKernelGGL(finalize_bc, dim3(12), dim3(512), 0, stream,
                     exer, Wg, asE, adE, Craw3, den3, Craw1, den1, b_gat, Bb, Cc);
  hipLaunchKernelGGL(finalize_exer, dim3(1), dim3(512), 0, stream,
                     exer, Bb, Cc, attn_w, attn_b, out + 262144);
}

// Round 2
// 474.700 us; speedup vs baseline: 1.4107x; 1.4107x over previous
//
#include <hip/hip_runtime.h>

typedef __attribute__((ext_vector_type(4))) float f4;
typedef __attribute__((ext_vector_type(8))) short s8;

__device__ __forceinline__ unsigned short f2bf(float x){
  unsigned u = __float_as_uint(x);
  u += 0x7fffu + ((u >> 16) & 1u);
  return (unsigned short)(u >> 16);
}
__device__ __forceinline__ float lrelu(float v){ return v > 0.f ? v : 0.2f * v; }

__device__ __forceinline__ void gload16(const unsigned short* g, unsigned short* l){
  __builtin_amdgcn_global_load_lds((const __attribute__((address_space(1))) unsigned int*)g,
                                   (__attribute__((address_space(3))) unsigned int*)l, 16, 0, 0);
}

// ---------------- prep 1: zero accumulators + p/q = W @ a_src / a_dst ----------------
__global__ void prep_pq(const float* __restrict__ Wg, const float* __restrict__ a_src,
                        const float* __restrict__ a_dst, float* __restrict__ pq,
                        float* __restrict__ zbase){
  int tid = blockIdx.x * 256 + threadIdx.x;
  for (int i = tid; i < 6156; i += gridDim.x * 256) zbase[i] = 0.f;  // Craw3,Craw1,den3,den1
  int wid = tid >> 6, lane = tid & 63;
  for (int task = wid; task < 4096; task += gridDim.x * 4){
    int g = task >> 10, isq = (task >> 9) & 1, r = task & 511;
    const float* w = Wg + ((g * 512 + r) << 9);
    const float* a = (isq ? a_dst : a_src) + g * 512;
    float s = 0.f;
    for (int i = lane; i < 512; i += 64) s += w[i] * a[i];
    for (int off = 32; off; off >>= 1) s += __shfl_down(s, off);
    if (lane == 0) pq[task] = s;
  }
}

// ---------------- prep 2: W2^T, W0^T as bf16 (n-major, contiguous k) ----------------
__global__ void prep_wt(const float* __restrict__ Wg, unsigned short* __restrict__ W2T,
                        unsigned short* __restrict__ W0T){
  __shared__ float tile[32][33];
  const int b = blockIdx.x;
  const int m = b >> 8;                      // 0: W2 -> W2T, 1: W0 -> W0T
  const int kb = (b & 15) * 32;
  const int nb = ((b >> 4) & 15) * 32;
  const float* W = Wg + (m == 0 ? 2 * 262144 : 0);
  unsigned short* WT = (m == 0) ? W2T : W0T;
  const int tx = threadIdx.x & 31, ty = threadIdx.x >> 5;
  #pragma unroll
  for (int i = 0; i < 32; i += 8) tile[ty + i][tx] = W[(kb + ty + i) * 512 + nb + tx];
  __syncthreads();
  #pragma unroll
  for (int i = 0; i < 32; i += 8) WT[(nb + ty + i) * 512 + kb + tx] = f2bf(tile[tx][ty + i]);
}

// ---------------- prep 3: exercise scalars + HE_g = exer_emb @ W_g ----------------
__global__ void prep_he(const float* __restrict__ exer, const float* __restrict__ Wg,
                        const float* __restrict__ pq, float* __restrict__ asE,
                        float* __restrict__ adE, float* __restrict__ HE2,
                        float* __restrict__ HE0){
  const int b = blockIdx.x;           // 0..11
  const int g = (b < 6) ? 0 : 2;
  const int e = b % 6;
  __shared__ float xs[512];
  const int t = threadIdx.x;          // 512
  xs[t] = exer[e * 512 + t];
  __syncthreads();
  const int wid = t >> 6, lane = t & 63;
  if (wid < 4){
    int gg = g + (wid >> 1), isq = wid & 1;
    const float* v = pq + gg * 1024 + isq * 512;
    float s = 0.f;
    for (int i = lane; i < 512; i += 64) s += xs[i] * v[i];
    for (int off = 32; off; off >>= 1) s += __shfl_down(s, off);
    if (lane == 0) (isq ? adE : asE)[gg * 6 + e] = s;
  }
  const float* W = Wg + g * 262144;
  float acc = 0.f;
  for (int k = 0; k < 512; k++) acc += xs[k] * W[k * 512 + t];
  ((g == 0) ? HE0 : HE2)[e * 512 + t] = acc;
}

// ---------------- pass 1: per-row scalars (receive softmax) + send-side accumulation ----------------
template<int DEG>
__launch_bounds__(256)
__global__ void pass1(const float* __restrict__ x, const float* __restrict__ pq,
                      int gA, int gB,
                      const float* __restrict__ asE, const float* __restrict__ adE,
                      float* __restrict__ alph, const int* __restrict__ idx,
                      float* __restrict__ Craw, float* __restrict__ den, int M)
{
  __shared__ float sC[3072];
  __shared__ float sDen[6];
  const int tid = threadIdx.x, lane = tid & 63, wid = tid >> 6;
  for (int i = tid; i < 3072; i += 256) sC[i] = 0.f;
  if (tid < 6) sDen[tid] = 0.f;

  const int kb = lane * 8;
  const float* pqA = pq + gA * 1024;
  const float* pqB = pq + gB * 1024;
  f4 pA0 = *(const f4*)(pqA + kb),       pA1 = *(const f4*)(pqA + kb + 4);
  f4 qA0 = *(const f4*)(pqA + 512 + kb), qA1 = *(const f4*)(pqA + 512 + kb + 4);
  f4 pB0 = *(const f4*)(pqB + kb),       pB1 = *(const f4*)(pqB + kb + 4);
  float aseR = asE[gA * 6 + (lane % 6)];
  float adeR = adE[gB * 6 + (lane % 6)];

  float cacc[6][8];
  #pragma unroll
  for (int e = 0; e < 6; e++)
    #pragma unroll
    for (int i = 0; i < 8; i++) cacc[e][i] = 0.f;
  float dacc[6] = {0.f,0.f,0.f,0.f,0.f,0.f};
  __syncthreads();

  const int gw = blockIdx.x * 4 + wid, nw = gridDim.x * 4;
  for (int r = gw; r < M; r += nw){
    const float* xr = x + (size_t)r * 512;
    f4 x0 = *(const f4*)(xr + kb), x1 = *(const f4*)(xr + kb + 4);
    float dP = 0.f, dQ = 0.f, dB = 0.f;
    #pragma unroll
    for (int i = 0; i < 4; i++){
      dP += x0[i]*pA0[i] + x1[i]*pA1[i];
      dQ += x0[i]*qA0[i] + x1[i]*qA1[i];
      dB += x0[i]*pB0[i] + x1[i]*pB1[i];
    }
    #pragma unroll
    for (int off = 1; off < 64; off <<= 1){
      dP += __shfl_xor(dP, off); dQ += __shfl_xor(dQ, off); dB += __shfl_xor(dB, off);
    }
    int ei[DEG];
    #pragma unroll
    for (int j = 0; j < DEG; j++) ei[j] = idx[r * DEG + j];
    float scS = lrelu(dP + dQ);
    float sc[DEG], m = scS;
    #pragma unroll
    for (int j = 0; j < DEG; j++){ sc[j] = lrelu(__shfl(aseR, ei[j]) + dQ); m = fmaxf(m, sc[j]); }
    float eS = __expf(scS - m), sum = eS;
    float ev[DEG];
    #pragma unroll
    for (int j = 0; j < DEG; j++){ ev[j] = __expf(sc[j] - m); sum += ev[j]; }
    float inv = 1.f / sum;
    // write [alpha_self, coef0..5, 0]
    float val = 0.f;
    if (lane == 0) val = eS * inv;
    else if (lane < 7){
      #pragma unroll
      for (int j = 0; j < DEG; j++) val += (ei[j] == lane - 1) ? ev[j] * inv : 0.f;
    }
    if (lane < 8) alph[(size_t)r * 8 + lane] = val;
    // send-side weights
    float wj[DEG];
    #pragma unroll
    for (int j = 0; j < DEG; j++) wj[j] = __expf(lrelu(dB + __shfl(adeR, ei[j])));
    #pragma unroll
    for (int e = 0; e < 6; e++){
      float we = 0.f;
      #pragma unroll
      for (int j = 0; j < DEG; j++) we += (ei[j] == e) ? wj[j] : 0.f;
      dacc[e] += we;
      #pragma unroll
      for (int i = 0; i < 4; i++){ cacc[e][i] += we * x0[i]; cacc[e][4+i] += we * x1[i]; }
    }
  }
  // block-level reduction
  #pragma unroll
  for (int e = 0; e < 6; e++)
    #pragma unroll
    for (int i = 0; i < 8; i++)
      atomicAdd(&sC[e * 512 + kb + i], cacc[e][i]);
  if (lane == 0){
    #pragma unroll
    for (int e = 0; e < 6; e++) atomicAdd(&sDen[e], dacc[e]);
  }
  __syncthreads();
  for (int i = tid; i < 3072; i += 256){
    float v = sC[i];
    if (v != 0.f) atomicAdd(&Craw[i], v);
  }
  if (tid < 6) atomicAdd(&den[tid], sDen[tid]);
}

// ---------------- pass 2: 128x128 MFMA GEMM with fused GAT epilogue ----------------
__launch_bounds__(256, 2)
__global__ void gemm_ep(const float* __restrict__ x, const unsigned short* __restrict__ WT,
                        const float* __restrict__ alph, const float* __restrict__ HE,
                        const float* __restrict__ bA, float* __restrict__ outp, int M)
{
  __shared__ __align__(16) unsigned short sA[4096];
  __shared__ __align__(16) unsigned short sB[4096];
  __shared__ __align__(16) float sAl[1024];
  __shared__ __align__(16) float sHEb[768];
  __shared__ __align__(16) float sB2[128];

  // bijective XCD swizzle, nb-fastest so each XCD reuses A-tiles and keeps B panels resident
  const int nwg = gridDim.x;
  const int q = nwg >> 3, rr = nwg & 7, xcd = blockIdx.x & 7, pos = blockIdx.x >> 3;
  const int wid = (xcd < rr ? xcd * (q + 1) : rr * (q + 1) + (xcd - rr) * q) + pos;
  const int mb = wid >> 2, nb = wid & 3;
  const int r0 = mb * 128, n0 = nb * 128;
  const int tid = threadIdx.x, lane = tid & 63, w = tid >> 6;
  const int wr = w >> 1, wc = w & 1, l16 = lane & 15, lhi = lane >> 4;

  { int row = min(r0 + (tid >> 1), M - 1);
    *(f4*)(sAl + tid * 4) = *(const f4*)(alph + (size_t)row * 8 + (tid & 1) * 4); }
  if (tid < 192) *(f4*)(sHEb + tid * 4) = *(const f4*)(HE + (tid >> 5) * 512 + n0 + (tid & 31) * 4);
  else if (tid < 224) *(f4*)(sB2 + (tid - 192) * 4) = *(const f4*)(bA + n0 + (tid - 192) * 4);

  const int sRow = tid >> 2, sK = (tid & 3) * 8;
  const float* xA0 = x + (size_t)min(r0 + sRow, M - 1) * 512 + sK;
  const float* xA1 = x + (size_t)min(r0 + 64 + sRow, M - 1) * 512 + sK;
  const unsigned short* gB0 = WT + (size_t)(n0 + sRow) * 512 + sK;
  const unsigned short* gB1 = WT + (size_t)(n0 + 64 + sRow) * 512 + sK;
  unsigned short* lA0 = sA + sRow * 32 + sK;
  unsigned short* lA1 = sA + (64 + sRow) * 32 + sK;
  unsigned short* lB0 = sB + sRow * 32 + sK;
  unsigned short* lB1 = sB + (64 + sRow) * 32 + sK;

  f4 acc[4][4];
  #pragma unroll
  for (int m = 0; m < 4; m++)
    #pragma unroll
    for (int n = 0; n < 4; n++) acc[m][n] = (f4){0.f, 0.f, 0.f, 0.f};

  f4 n00 = *(const f4*)(xA0),     n01 = *(const f4*)(xA0 + 4);
  f4 n10 = *(const f4*)(xA1),     n11 = *(const f4*)(xA1 + 4);

  for (int kt = 0; kt < 16; kt++){
    const int ko = kt * 32;
    gload16(gB0 + ko, lB0);
    gload16(gB1 + ko, lB1);
    s8 p0, p1;
    #pragma unroll
    for (int i = 0; i < 4; i++){
      p0[i]   = (short)f2bf(n00[i]); p0[4+i] = (short)f2bf(n01[i]);
      p1[i]   = (short)f2bf(n10[i]); p1[4+i] = (short)f2bf(n11[i]);
    }
    *(s8*)lA0 = p0; *(s8*)lA1 = p1;
    if (kt < 15){
      n00 = *(const f4*)(xA0 + ko + 32); n01 = *(const f4*)(xA0 + ko + 36);
      n10 = *(const f4*)(xA1 + ko + 32); n11 = *(const f4*)(xA1 + ko + 36);
    }
    __syncthreads();
    s8 af[4], bfr[4];
    #pragma unroll
    for (int m = 0; m < 4; m++) af[m] = *(const s8*)(sA + (wr * 64 + m * 16 + l16) * 32 + lhi * 8);
    #pragma unroll
    for (int n = 0; n < 4; n++) bfr[n] = *(const s8*)(sB + (wc * 64 + n * 16 + l16) * 32 + lhi * 8);
    #pragma unroll
    for (int m = 0; m < 4; m++)
      #pragma unroll
      for (int n = 0; n < 4; n++)
        acc[m][n] = __builtin_amdgcn_mfma_f32_16x16x32_bf16(af[m], bfr[n], acc[m][n], 0, 0, 0);
    __syncthreads();
  }

  // epilogue: out = x + a_self*(x@W) + sum_e coef_e*HE[e] + b
  #pragma unroll
  for (int m = 0; m < 4; m++){
    const int rl = wr * 64 + m * 16 + lhi * 4;
    #pragma unroll
    for (int n = 0; n < 4; n++){
      const int cl = wc * 64 + n * 16 + l16;
      const int gc = n0 + cl;
      const float hb = sB2[cl];
      #pragma unroll
      for (int j = 0; j < 4; j++){
        const int row = r0 + rl + j;
        if (row < M){
          const float* al = sAl + (rl + j) * 8;
          float v = x[(size_t)row * 512 + gc] + al[0] * acc[m][n][j] + hb;
          #pragma unroll
          for (int e = 0; e < 6; e++) v += al[1 + e] * sHEb[e * 128 + cl];
          outp[(size_t)row * 512 + gc] = v;
        }
      }
    }
  }
}

// ---------------- finalize B (GAT1) and C (GAT3) for the 6 exercises ----------------
__global__ void finalize_bc(const float* __restrict__ exer, const float* __restrict__ Wg,
                            const float* __restrict__ asE, const float* __restrict__ adE,
                            const float* __restrict__ Craw3, const float* __restrict__ den3,
                            const float* __restrict__ Craw1, const float* __restrict__ den1,
                            const float* __restrict__ b_gat, float* __restrict__ B,
                            float* __restrict__ C){
  const int b = blockIdx.x;          // 0..11
  const int isC = (b >= 6) ? 1 : 0;
  const int e = b % 6;
  const int g = isC ? 3 : 1;
  const float* Craw = isC ? Craw3 : Craw1;
  const float* den  = isC ? den3  : den1;
  __shared__ float mix[512];
  const int t = threadIdx.x;          // 512
  float aS = asE[g*6 + e], aD = adE[g*6 + e];
  float wself = __expf(lrelu(aS + aD));
  float dn = den[e] + wself;
  mix[t] = (Craw[e*512 + t] + wself * exer[e*512 + t]) / dn;
  __syncthreads();
  const float* W = Wg + g * 262144;
  float acc = 0.f;
  for (int k = 0; k < 512; k++) acc += mix[k] * W[k*512 + t];
  acc += b_gat[g*512 + t];
  (isC ? C : B)[e*512 + t] = acc;
}

// ---------------- final exercise attention + output ----------------
__global__ void finalize_exer(const float* __restrict__ exer, const float* __restrict__ B,
                              const float* __restrict__ C, const float* __restrict__ attn_w,
                              const float* __restrict__ attn_b, float* __restrict__ outE){
  __shared__ float s1[6], s2[6];
  const int t = threadIdx.x, wid = t >> 6, lane = t & 63;
  for (int task = wid; task < 12; task += 8){
    int e = task >> 1, which = task & 1;
    const float* w = attn_w + (which + 1) * 1024;
    const float* X = exer + e * 512;
    const float* Y = (which ? C : B) + e * 512;
    float s = 0.f;
    for (int i = lane; i < 512; i += 64) s += X[i] * w[i] + Y[i] * w[512 + i];
    for (int off = 32; off; off >>= 1) s += __shfl_down(s, off);
    if (lane == 0) (which ? s2 : s1)[e] = s + attn_b[which + 1];
  }
  __syncthreads();
  for (int i = t; i < 3072; i += 512){
    int e = i >> 9;
    float a = s1[e], b = s2[e];
    float m = fmaxf(a, b);
    float ea = __expf(a - m), eb = __expf(b - m);
    float inv = 1.f / (ea + eb);
    outE[i] = exer[i] + (ea * inv) * B[i] + (eb * inv) * C[i];
  }
}

extern "C" void kernel_launch(void* const* d_in, const int* in_sizes, int n_in,
                              void* d_out, int out_size, void* d_ws, size_t ws_size,
                              hipStream_t stream){
  const float* kn     = (const float*)d_in[0];
  const float* exer   = (const float*)d_in[1];
  const float* stu    = (const float*)d_in[2];
  const float* Wg     = (const float*)d_in[3];
  const float* a_src  = (const float*)d_in[4];
  const float* a_dst  = (const float*)d_in[5];
  const float* b_gat  = (const float*)d_in[6];
  const float* attn_w = (const float*)d_in[7];
  const float* attn_b = (const float*)d_in[8];
  const int*   e_ke   = (const int*)d_in[9];
  const int*   e_ue   = (const int*)d_in[11];
  float* out = (float*)d_out;

  unsigned short* W2T = (unsigned short*)d_ws;
  unsigned short* W0T = W2T + 262144;
  float* pq    = (float*)(W0T + 262144);
  float* asE   = pq + 4096;
  float* adE   = asE + 24;
  float* HE2   = adE + 24;
  float* HE0   = HE2 + 3072;
  float* Craw3 = HE0 + 3072;
  float* Craw1 = Craw3 + 3072;
  float* den3  = Craw1 + 3072;
  float* den1  = den3 + 6;
  float* Bb    = den1 + 6;
  float* Cc    = Bb + 3072;
  float* alphS = Cc + 3072;
  float* alphK = alphS + 400000;

  hipLaunchKernelGGL(prep_pq, dim3(256), dim3(256), 0, stream, Wg, a_src, a_dst, pq, Craw3);
  hipLaunchKernelGGL(prep_wt, dim3(512), dim3(256), 0, stream, Wg, W2T, W0T);
  hipLaunchKernelGGL(prep_he, dim3(12), dim3(512), 0, stream, exer, Wg, pq, asE, adE, HE2, HE0);

  // pass 1: students (receive GAT2, send GAT3) and knowledge (receive GAT0, send GAT1)
  hipLaunchKernelGGL((pass1<3>), dim3(768), dim3(256), 0, stream,
                     stu, pq, 2, 3, asE, adE, alphS, e_ue, Craw3, den3, 50000);
  hipLaunchKernelGGL((pass1<4>), dim3(8), dim3(256), 0, stream,
                     kn, pq, 0, 1, asE, adE, alphK, e_ke, Craw1, den1, 512);

  // pass 2: fused GEMM + epilogue
  hipLaunchKernelGGL(gemm_ep, dim3(1564), dim3(256), 0, stream,
                     stu, W2T, alphS, HE2, b_gat + 1024, out + 265216, 50000);
  hipLaunchKernelGGL(gemm_ep, dim3(16), dim3(256), 0, stream,
                     kn, W0T, alphK, HE0, b_gat, out, 512);

  hipLaunchKernelGGL(finalize_bc, dim3(12), dim3(512), 0, stream,
                     exer, Wg, asE, adE, Craw3, den3, Craw1, den1, b_gat, Bb, Cc);
  hipLaunchKernelGGL(finalize_exer, dim3(1), dim3(512), 0, stream,
                     exer, Bb, Cc, attn_w, attn_b, out + 262144);
}